// Round 5
// baseline (8510.452 us; speedup 1.0000x reference)
//
#include <hip/hip_runtime.h>

#define TT   1024
#define BB   64
#define DIN  256
#define HH   512
#define ROWS 4               // batch rows per block (was 8)
#define HCW    36            // padded h-chunk stride in words (32 + 4)
#define HROW_W (16 * HCW)    // 576 words per staged h row
#define XROW_W 264           // staged x row stride in words (256 + 8)
#define EXQ  (BB * HH)       // 32768 tuples per parity buffer

typedef unsigned long long u64;

// tanh via expf: avoids ocml tanhf slow path; clamp keeps exp finite
// (tanh(15) rounds to 1.0f exactly, so the clamp is value-preserving).
__device__ __forceinline__ float tanh_f(float x) {
    float xx = fminf(15.f, fmaxf(-15.f, x));
    float e2 = expf(2.f * xx);
    return 1.f - 2.f / (e2 + 1.f);
}

// Persistent kernel, 512 blocks = 16 rowgrps (4 batch rows) x 32 colgrps
// (16 h-cols), 2 blocks/CU (__launch_bounds__(256,2): VGPR<=256, LDS
// 34.4KB/block -> both fit 2/CU). vs r4 (6.7ms, passed):
//  - serial path halved: 4 rows/block -> h-GEMM per thread 512 fma (was
//    1024), tuple reads 8/thread (was 16).
//  - 2 waves/SIMD: rg = bid>>5 makes co-resident pairs (bid, bid+256)
//    DIFFERENT rowgroups -> independent barrier domains -> mutual stall
//    hiding (poll, barriers, LDS latency).
// h exchange: identical self-validating 8B tuple protocol to r4
// (float h_bits | (t+1)<<32, double-buffered by t&1, relaxed agent
// atomics, no fences, no flags, no drains). Same deadlock-safety and
// double-buffer lockstep argument as r4.
__global__ __launch_bounds__(256, 2)
void lstm_persist(const float* __restrict__ x_all,  // [1024][64][256]
                  const float* __restrict__ W4,     // [768][2048]
                  const float* __restrict__ b4,     // [2048]
                  float* out,                        // [1024][64][512] + hx + cx
                  u64* exch)                         // [2][64][512] tuples
{
    __shared__ float sH[ROWS * HROW_W];      // staged h_{t-1}, 9.2 KB
    __shared__ float sX[ROWS * XROW_W];      // staged x_t, 4.2 KB
    __shared__ float sP[ROWS * 64 * 20];     // K-split partials, 20.5 KB
    __shared__ float sC[ROWS * 16];          // c state, block-local

    const int tid = threadIdx.x;
    const int bid = blockIdx.x;
    const int rg  = bid >> 5;                // rowgrp 0..15
    const int cgb = bid & 31;                // colgrp 0..31
    const int r0  = rg * ROWS;
    const int hc0 = cgb * 16;

    const int cg = tid & 15;                 // owns 4 z-cols
    const int kc = tid >> 4;                 // K-chunk 0..15
    const int l0 = cg * 4;
    const int gate = l0 >> 4;
    const int zc0 = gate * 512 + hc0 + (l0 & 15);

    // ---- x staging offsets: 256 float4s, 1/thread ----
    const int xrow = tid >> 6, xkq = (tid & 63) * 4;
    const int xL = xrow * XROW_W + xkq;
    const int xG = (r0 + xrow) * DIN + xkq;

    const u64* exrd0 = exch + (size_t)r0 * HH + tid;   // + parity*EXQ + 256*s

    // ---- one-time: Wh slice (rows DIN + kc*32..+31, cols zc0..+3) ----
    float4 w0[8], w1[8], w2[8], w3[8];
    #pragma unroll
    for (int k4 = 0; k4 < 8; ++k4) {
        const float* base = W4 + (size_t)(DIN + kc * 32 + 4 * k4) * 2048 + zc0;
        float4 t0 = *(const float4*)(base);
        float4 t1 = *(const float4*)(base + 2048);
        float4 t2 = *(const float4*)(base + 4096);
        float4 t3 = *(const float4*)(base + 6144);
        w0[k4] = make_float4(t0.x, t1.x, t2.x, t3.x);
        w1[k4] = make_float4(t0.y, t1.y, t2.y, t3.y);
        w2[k4] = make_float4(t0.z, t1.z, t2.z, t3.z);
        w3[k4] = make_float4(t0.w, t1.w, t2.w, t3.w);
    }
    // ---- one-time: Wx slice (rows kc*16..+15, cols zc0..+3), row-major ----
    float4 wx[16];
    #pragma unroll
    for (int kk = 0; kk < 16; ++kk)
        wx[kk] = *(const float4*)(W4 + (size_t)(kc * 16 + kk) * 2048 + zc0);

    float bias0 = 0.f, bias1 = 0.f, bias2 = 0.f, bias3 = 0.f;
    int exO = 0;
    if (tid < 64) {
        sC[tid] = 0.f;
        int hc = tid & 15;
        int rr = tid >> 4;
        exO = (r0 + rr) * HH + hc0 + hc;     // producer tuple slot
        bias0 = b4[0 * 512 + hc0 + hc];
        bias1 = b4[1 * 512 + hc0 + hc];
        bias2 = b4[2 * 512 + hc0 + hc];
        bias3 = b4[3 * 512 + hc0 + hc];
    }

    // ---- pre-stage x_0 ----
    *(float4*)&sX[xL] = *(const float4*)(x_all + xG);
    __syncthreads();

    for (int t = 0; t < TT; ++t) {
        // ---- (A) issue x_{t+1} load; x-part partials from sX ----
        const bool havex = (t + 1 < TT);
        float4 xr0;
        if (havex)
            xr0 = *(const float4*)(x_all + (size_t)(t + 1) * (BB * DIN) + xG);
        float ac0[ROWS], ac1[ROWS], ac2[ROWS], ac3[ROWS];
        #pragma unroll
        for (int r = 0; r < ROWS; ++r) {
            const float* xp = &sX[r * XROW_W + kc * 16];
            float ax = 0.f, ay = 0.f, az = 0.f, aw = 0.f;
            #pragma unroll
            for (int q = 0; q < 4; ++q) {
                float4 x4 = *(const float4*)(xp + 4 * q);
                ax = fmaf(x4.x, wx[4*q+0].x, ax); ax = fmaf(x4.y, wx[4*q+1].x, ax);
                ax = fmaf(x4.z, wx[4*q+2].x, ax); ax = fmaf(x4.w, wx[4*q+3].x, ax);
                ay = fmaf(x4.x, wx[4*q+0].y, ay); ay = fmaf(x4.y, wx[4*q+1].y, ay);
                ay = fmaf(x4.z, wx[4*q+2].y, ay); ay = fmaf(x4.w, wx[4*q+3].y, ay);
                az = fmaf(x4.x, wx[4*q+0].z, az); az = fmaf(x4.y, wx[4*q+1].z, az);
                az = fmaf(x4.z, wx[4*q+2].z, az); az = fmaf(x4.w, wx[4*q+3].z, az);
                aw = fmaf(x4.x, wx[4*q+0].w, aw); aw = fmaf(x4.y, wx[4*q+1].w, aw);
                aw = fmaf(x4.z, wx[4*q+2].w, aw); aw = fmaf(x4.w, wx[4*q+3].w, aw);
            }
            ac0[r] = ax; ac1[r] = ay; ac2[r] = az; ac3[r] = aw;
        }
        __syncthreads();                                  // BAR1 (sX, sH safe)

        // ---- (C) tuple-read h_{t-1} (the sync) -> sH; refill sX ----
        // tuple s: linear l = tid + 256*s over 4 rows x 512 cols:
        //   row = s>>1, col = tid + ((s&1)<<8)
        if (t > 0) {
            const unsigned want = (unsigned)t;            // seq stored = t_prod+1
            const u64* tb = exrd0 + (size_t)((t & 1) ^ 1) * EXQ;
            u64 tv[8];
            #pragma unroll
            for (int s = 0; s < 8; ++s)
                tv[s] = __hip_atomic_load(tb + 256 * s, __ATOMIC_RELAXED,
                                          __HIP_MEMORY_SCOPE_AGENT);
            bool again;
            do {
                again = false;
                #pragma unroll
                for (int s = 0; s < 8; ++s) {
                    if ((unsigned)(tv[s] >> 32) != want) {
                        tv[s] = __hip_atomic_load(tb + 256 * s, __ATOMIC_RELAXED,
                                                  __HIP_MEMORY_SCOPE_AGENT);
                        again = true;
                    }
                }
            } while (again);
            #pragma unroll
            for (int s = 0; s < 8; ++s) {
                int co = (tid + ((s & 1) << 8));
                int off = (s >> 1) * HROW_W + (co >> 5) * HCW + (co & 31);
                sH[off] = __uint_as_float((unsigned)tv[s]);
            }
        } else {
            #pragma unroll
            for (int s = 0; s < 8; ++s) {
                int co = (tid + ((s & 1) << 8));
                int off = (s >> 1) * HROW_W + (co >> 5) * HCW + (co & 31);
                sH[off] = 0.f;                            // h0 = zeros
            }
        }
        if (havex)
            *(float4*)&sX[xL] = xr0;
        __syncthreads();                                  // BAR2 (sH, sX ready)

        // ---- (D) h-part: accumulate over this thread's 32-K ----
        #pragma unroll
        for (int r = 0; r < ROWS; ++r) {
            const float* hp = &sH[r * HROW_W + kc * HCW];
            float ax = ac0[r], ay = ac1[r], az = ac2[r], aw = ac3[r];
            #pragma unroll
            for (int k4 = 0; k4 < 8; ++k4) {
                float4 h4 = *(const float4*)(hp + 4 * k4);
                ax = fmaf(h4.x, w0[k4].x, ax); ax = fmaf(h4.y, w0[k4].y, ax);
                ax = fmaf(h4.z, w0[k4].z, ax); ax = fmaf(h4.w, w0[k4].w, ax);
                ay = fmaf(h4.x, w1[k4].x, ay); ay = fmaf(h4.y, w1[k4].y, ay);
                ay = fmaf(h4.z, w1[k4].z, ay); ay = fmaf(h4.w, w1[k4].w, ay);
                az = fmaf(h4.x, w2[k4].x, az); az = fmaf(h4.y, w2[k4].y, az);
                az = fmaf(h4.z, w2[k4].z, az); az = fmaf(h4.w, w2[k4].w, az);
                aw = fmaf(h4.x, w3[k4].x, aw); aw = fmaf(h4.y, w3[k4].y, aw);
                aw = fmaf(h4.z, w3[k4].z, aw); aw = fmaf(h4.w, w3[k4].w, aw);
            }
            float* pp = &sP[(r * 64 + l0) * 20];
            pp[0 * 20 + ((kc + 5 * cg + 0) & 15)] = ax;
            pp[1 * 20 + ((kc + 5 * cg + 1) & 15)] = ay;
            pp[2 * 20 + ((kc + 5 * cg + 2) & 15)] = az;
            pp[3 * 20 + ((kc + 5 * cg + 3) & 15)] = aw;
        }
        __syncthreads();                                  // BAR3 (sP ready)

        // ---- (F) reduce partials, gates, c/h update, publish (64 thr) ----
        if (tid < 64) {
            int rr = tid >> 4;
            int hc = tid & 15;
            float z[4];
            #pragma unroll
            for (int g = 0; g < 4; ++g) {
                const float* pp = &sP[(rr * 64 + g * 16 + hc) * 20];
                float s = 0.f;
                #pragma unroll
                for (int q = 0; q < 4; ++q) {
                    int off = 4 * ((rr + q) & 3);
                    float4 a = *(const float4*)(pp + off);
                    s += ((a.x + a.y) + (a.z + a.w));
                }
                z[g] = s;
            }
            z[0] += bias0; z[1] += bias1; z[2] += bias2; z[3] += bias3;
            float f  = 1.f / (1.f + expf(-z[0]));
            float ii = 1.f / (1.f + expf(-z[1]));
            float gg = tanh_f(z[2]);
            float o  = 1.f / (1.f + expf(-z[3]));
            float cn = f * sC[rr * 16 + hc] + ii * gg;
            sC[rr * 16 + hc] = cn;
            float hn = o * tanh_f(cn);
            // publish FIRST (serial-path store), fire-and-forget
            u64 pk = ((u64)(unsigned)(t + 1) << 32) | (u64)__float_as_uint(hn);
            __hip_atomic_store(exch + (size_t)(t & 1) * EXQ + exO, pk,
                               __ATOMIC_RELAXED, __HIP_MEMORY_SCOPE_AGENT);
            // graded history: plain store (write-only during kernel)
            out[((size_t)t * BB + (r0 + rr)) * HH + hc0 + hc] = hn;
            if (t == TT - 1) {
                out[(size_t)TT * BB * HH + (size_t)(r0 + rr) * HH + hc0 + hc] = hn;            // hx
                out[(size_t)TT * BB * HH + BB * HH + (size_t)(r0 + rr) * HH + hc0 + hc] = cn;  // cx
            }
        }
        // no BAR4: next-iter BAR1/BAR2 cover all sX/sH/sP hazards
    }
}

extern "C" void kernel_launch(void* const* d_in, const int* in_sizes, int n_in,
                              void* d_out, int out_size, void* d_ws, size_t ws_size,
                              hipStream_t stream) {
    const float* x_all = (const float*)d_in[0];
    const float* W4    = (const float*)d_in[1];
    const float* b4    = (const float*)d_in[2];
    float* out = (float*)d_out;

    u64* exch = (u64*)d_ws;                  // [2][64][512] tuples, 512 KB

    hipMemsetAsync(d_ws, 0, 2 * (size_t)EXQ * sizeof(u64), stream);

    lstm_persist<<<dim3(512), dim3(256), 0, stream>>>(x_all, W4, b4, out, exch);
}

// Round 6
// 4577.375 us; speedup vs baseline: 1.8592x; 1.8592x over previous
//
#include <hip/hip_runtime.h>

#define TT   1024
#define BB   64
#define DIN  256
#define HH   512
#define ROWS 8
#define HCW    20            // padded h-chunk stride in words (16 + 4)
#define HROW_W (32 * HCW)    // 640 words per staged h row
#define XCW    12            // padded x-chunk stride in words (8 + 4)
#define XROW_W (32 * XCW)    // 384 words per staged x row
#define EXQ  (BB * HH)       // 32768 tuples per parity buffer

typedef unsigned long long u64;

// tanh via expf: avoids ocml tanhf slow path; clamp keeps exp finite
// (tanh(15) rounds to 1.0f exactly, so the clamp is value-preserving).
__device__ __forceinline__ float tanh_f(float x) {
    float xx = fminf(15.f, fmaxf(-15.f, x));
    float e2 = expf(2.f * xx);
    return 1.f - 2.f / (e2 + 1.f);
}

// Persistent kernel: 256 blocks (8 rowgrps x 32 colgrps), 1 block/CU —
// co-residency guarantee IDENTICAL to the passing r4. TLP comes from
// 512-thread blocks: 8 waves -> 2 waves/SIMD fill each other's LDS/sync
// stalls. Per-thread register pressure halved by 32-way K-split
// (Wh 16K x 4cols = 64 VGPR, Wx 8K = 32 VGPR; ~170 total, no cap, no
// spill — r5's regression was launch_bounds(256,2)'s 128-VGPR cap
// spilling W to scratch: FETCH 212MB -> 3.4GB).
//
// h exchange: identical self-validating 8B tuple protocol to r4
// (float h_bits | (t+1)<<32, double-buffered by t&1, relaxed agent
// atomics, no fences, no flags, no drains). Same deadlock-safety and
// double-buffer lockstep argument as r4.
__global__ __launch_bounds__(512, 1)
void lstm_persist(const float* __restrict__ x_all,  // [1024][64][256]
                  const float* __restrict__ W4,     // [768][2048]
                  const float* __restrict__ b4,     // [2048]
                  float* out,                        // [1024][64][512] + hx + cx
                  u64* exch)                         // [2][64][512] tuples
{
    __shared__ float sH[ROWS * HROW_W];      // staged h_{t-1}, 20.5 KB
    __shared__ float sX[ROWS * XROW_W];      // staged x_t, 12.3 KB
    __shared__ float sP[ROWS * 64 * 36];     // 32 K-split partials, 73.7 KB
    __shared__ float sC[ROWS * 16];          // c state, block-local

    const int tid = threadIdx.x;
    const int bid = blockIdx.x;
    const int rg  = bid & 7;                 // rowgrp (bid&7: XCD-aligned)
    const int cgb = bid >> 3;                // colgrp 0..31
    const int r0  = rg * ROWS;
    const int hc0 = cgb * 16;

    const int cg = tid & 15;                 // owns 4 z-cols
    const int kc = tid >> 4;                 // K-chunk 0..31
    const int l0 = cg * 4;
    const int gate = l0 >> 4;
    const int zc0 = gate * 512 + hc0 + (l0 & 15);

    // ---- x staging offsets: 512 float4s, 1/thread ----
    const int xrow = tid >> 6, xkq = (tid & 63) * 4;
    const int xL = xrow * XROW_W + (xkq >> 3) * XCW + (xkq & 7);
    const int xG = (r0 + xrow) * DIN + xkq;

    const u64* exrd0 = exch + (size_t)r0 * HH + tid;   // + parity*EXQ + 512*s

    // ---- one-time: Wh slice (rows DIN + kc*16..+15, cols zc0..+3) ----
    float4 w0[4], w1[4], w2[4], w3[4];
    #pragma unroll
    for (int k4 = 0; k4 < 4; ++k4) {
        const float* base = W4 + (size_t)(DIN + kc * 16 + 4 * k4) * 2048 + zc0;
        float4 t0 = *(const float4*)(base);
        float4 t1 = *(const float4*)(base + 2048);
        float4 t2 = *(const float4*)(base + 4096);
        float4 t3 = *(const float4*)(base + 6144);
        w0[k4] = make_float4(t0.x, t1.x, t2.x, t3.x);
        w1[k4] = make_float4(t0.y, t1.y, t2.y, t3.y);
        w2[k4] = make_float4(t0.z, t1.z, t2.z, t3.z);
        w3[k4] = make_float4(t0.w, t1.w, t2.w, t3.w);
    }
    // ---- one-time: Wx slice (rows kc*8..+7, cols zc0..+3), row-major ----
    float4 wx[8];
    #pragma unroll
    for (int kk = 0; kk < 8; ++kk)
        wx[kk] = *(const float4*)(W4 + (size_t)(kc * 8 + kk) * 2048 + zc0);

    float bias0 = 0.f, bias1 = 0.f, bias2 = 0.f, bias3 = 0.f;
    int exO = 0;
    if (tid < 128) {
        sC[tid] = 0.f;
        int hc = tid & 15;
        int rr = tid >> 4;
        exO = (r0 + rr) * HH + hc0 + hc;     // producer tuple slot
        bias0 = b4[0 * 512 + hc0 + hc];
        bias1 = b4[1 * 512 + hc0 + hc];
        bias2 = b4[2 * 512 + hc0 + hc];
        bias3 = b4[3 * 512 + hc0 + hc];
    }

    // ---- pre-stage x_0 ----
    *(float4*)&sX[xL] = *(const float4*)(x_all + xG);
    __syncthreads();

    for (int t = 0; t < TT; ++t) {
        // ---- (A) issue x_{t+1} load; x-part partials (fills poll wait) ----
        const bool havex = (t + 1 < TT);
        float4 xr0;
        if (havex)
            xr0 = *(const float4*)(x_all + (size_t)(t + 1) * (BB * DIN) + xG);
        float ac0[ROWS], ac1[ROWS], ac2[ROWS], ac3[ROWS];
        #pragma unroll
        for (int r = 0; r < ROWS; ++r) {
            const float* xp = &sX[r * XROW_W + kc * XCW];
            float ax = 0.f, ay = 0.f, az = 0.f, aw = 0.f;
            #pragma unroll
            for (int q = 0; q < 2; ++q) {
                float4 x4 = *(const float4*)(xp + 4 * q);
                ax = fmaf(x4.x, wx[4*q+0].x, ax); ax = fmaf(x4.y, wx[4*q+1].x, ax);
                ax = fmaf(x4.z, wx[4*q+2].x, ax); ax = fmaf(x4.w, wx[4*q+3].x, ax);
                ay = fmaf(x4.x, wx[4*q+0].y, ay); ay = fmaf(x4.y, wx[4*q+1].y, ay);
                ay = fmaf(x4.z, wx[4*q+2].y, ay); ay = fmaf(x4.w, wx[4*q+3].y, ay);
                az = fmaf(x4.x, wx[4*q+0].z, az); az = fmaf(x4.y, wx[4*q+1].z, az);
                az = fmaf(x4.z, wx[4*q+2].z, az); az = fmaf(x4.w, wx[4*q+3].z, az);
                aw = fmaf(x4.x, wx[4*q+0].w, aw); aw = fmaf(x4.y, wx[4*q+1].w, aw);
                aw = fmaf(x4.z, wx[4*q+2].w, aw); aw = fmaf(x4.w, wx[4*q+3].w, aw);
            }
            ac0[r] = ax; ac1[r] = ay; ac2[r] = az; ac3[r] = aw;
        }
        __syncthreads();                                  // BAR1 (sX, sH safe)

        // ---- (C) tuple-read h_{t-1} (the sync) -> sH; refill sX ----
        // tuple s: linear l = tid + 512*s over 8 rows x 512 cols
        if (t > 0) {
            const unsigned want = (unsigned)t;            // seq stored = t_prod+1
            const u64* tb = exrd0 + (size_t)((t & 1) ^ 1) * EXQ;
            u64 tv[8];
            #pragma unroll
            for (int s = 0; s < 8; ++s)
                tv[s] = __hip_atomic_load(tb + 512 * s, __ATOMIC_RELAXED,
                                          __HIP_MEMORY_SCOPE_AGENT);
            bool again;
            do {
                again = false;
                #pragma unroll
                for (int s = 0; s < 8; ++s) {
                    if ((unsigned)(tv[s] >> 32) != want) {
                        tv[s] = __hip_atomic_load(tb + 512 * s, __ATOMIC_RELAXED,
                                                  __HIP_MEMORY_SCOPE_AGENT);
                        again = true;
                    }
                }
            } while (again);
            #pragma unroll
            for (int s = 0; s < 8; ++s) {
                int l  = tid + 512 * s;
                int ro = l >> 9, co = l & 511;
                sH[ro * HROW_W + (co >> 4) * HCW + (co & 15)] =
                    __uint_as_float((unsigned)tv[s]);
            }
        } else {
            #pragma unroll
            for (int s = 0; s < 8; ++s) {
                int l  = tid + 512 * s;
                int ro = l >> 9, co = l & 511;
                sH[ro * HROW_W + (co >> 4) * HCW + (co & 15)] = 0.f;
            }
        }
        if (havex)
            *(float4*)&sX[xL] = xr0;
        __syncthreads();                                  // BAR2 (sH, sX ready)

        // ---- (D) h-part: accumulate over this thread's 16-K chunk ----
        #pragma unroll
        for (int r = 0; r < ROWS; ++r) {
            const float* hp = &sH[r * HROW_W + kc * HCW];
            float ax = ac0[r], ay = ac1[r], az = ac2[r], aw = ac3[r];
            #pragma unroll
            for (int k4 = 0; k4 < 4; ++k4) {
                float4 h4 = *(const float4*)(hp + 4 * k4);
                ax = fmaf(h4.x, w0[k4].x, ax); ax = fmaf(h4.y, w0[k4].y, ax);
                ax = fmaf(h4.z, w0[k4].z, ax); ax = fmaf(h4.w, w0[k4].w, ax);
                ay = fmaf(h4.x, w1[k4].x, ay); ay = fmaf(h4.y, w1[k4].y, ay);
                ay = fmaf(h4.z, w1[k4].z, ay); ay = fmaf(h4.w, w1[k4].w, ay);
                az = fmaf(h4.x, w2[k4].x, az); az = fmaf(h4.y, w2[k4].y, az);
                az = fmaf(h4.z, w2[k4].z, az); az = fmaf(h4.w, w2[k4].w, az);
                aw = fmaf(h4.x, w3[k4].x, aw); aw = fmaf(h4.y, w3[k4].y, aw);
                aw = fmaf(h4.z, w3[k4].z, aw); aw = fmaf(h4.w, w3[k4].w, aw);
            }
            float* pp = &sP[(r * 64 + l0) * 36];
            pp[0 * 36 + ((kc + 5 * cg + 0) & 31)] = ax;
            pp[1 * 36 + ((kc + 5 * cg + 1) & 31)] = ay;
            pp[2 * 36 + ((kc + 5 * cg + 2) & 31)] = az;
            pp[3 * 36 + ((kc + 5 * cg + 3) & 31)] = aw;
        }
        __syncthreads();                                  // BAR3 (sP ready)

        // ---- (F) reduce partials, gates, c/h update, publish (128 thr) ----
        if (tid < 128) {
            int rr = tid >> 4;
            int hc = tid & 15;
            float z[4];
            #pragma unroll
            for (int g = 0; g < 4; ++g) {
                const float* pp = &sP[(rr * 64 + g * 16 + hc) * 36];
                float s = 0.f;
                #pragma unroll
                for (int q = 0; q < 8; ++q) {
                    int off = 4 * ((rr + q) & 7);
                    float4 a = *(const float4*)(pp + off);
                    s += ((a.x + a.y) + (a.z + a.w));
                }
                z[g] = s;
            }
            z[0] += bias0; z[1] += bias1; z[2] += bias2; z[3] += bias3;
            float f  = 1.f / (1.f + expf(-z[0]));
            float ii = 1.f / (1.f + expf(-z[1]));
            float gg = tanh_f(z[2]);
            float o  = 1.f / (1.f + expf(-z[3]));
            float cn = f * sC[rr * 16 + hc] + ii * gg;
            sC[rr * 16 + hc] = cn;
            float hn = o * tanh_f(cn);
            // publish FIRST (serial-path store), fire-and-forget
            u64 pk = ((u64)(unsigned)(t + 1) << 32) | (u64)__float_as_uint(hn);
            __hip_atomic_store(exch + (size_t)(t & 1) * EXQ + exO, pk,
                               __ATOMIC_RELAXED, __HIP_MEMORY_SCOPE_AGENT);
            // graded history: plain store (write-only during kernel)
            out[((size_t)t * BB + (r0 + rr)) * HH + hc0 + hc] = hn;
            if (t == TT - 1) {
                out[(size_t)TT * BB * HH + (size_t)(r0 + rr) * HH + hc0 + hc] = hn;            // hx
                out[(size_t)TT * BB * HH + BB * HH + (size_t)(r0 + rr) * HH + hc0 + hc] = cn;  // cx
            }
        }
        // no BAR4: next-iter BAR1/BAR2 cover all sX/sH/sP hazards
    }
}

extern "C" void kernel_launch(void* const* d_in, const int* in_sizes, int n_in,
                              void* d_out, int out_size, void* d_ws, size_t ws_size,
                              hipStream_t stream) {
    const float* x_all = (const float*)d_in[0];
    const float* W4    = (const float*)d_in[1];
    const float* b4    = (const float*)d_in[2];
    float* out = (float*)d_out;

    u64* exch = (u64*)d_ws;                  // [2][64][512] tuples, 512 KB

    hipMemsetAsync(d_ws, 0, 2 * (size_t)EXQ * sizeof(u64), stream);

    lstm_persist<<<dim3(256), dim3(512), 0, stream>>>(x_all, W4, b4, out, exch);
}